// Round 4
// baseline (470.483 us; speedup 1.0000x reference)
//
#include <hip/hip_runtime.h>
#include <hip/hip_bf16.h>
#include <math.h>

typedef unsigned short u16;
typedef unsigned int   u32;
typedef short v8s __attribute__((ext_vector_type(8)));
typedef float v4f __attribute__((ext_vector_type(4)));
typedef float v2f __attribute__((ext_vector_type(2)));
#define DEV static __device__ __forceinline__

DEV float u2f(u16 u){ union{u32 i; float f;} v; v.i = ((u32)u)<<16; return v.f; }
DEV u16   f2u(float f){ union{float ff; u32 i;} v; v.ff = f; u32 r = v.i + 0x7fffu + ((v.i>>16)&1u); return (u16)(r>>16); }
DEV float lrelu02(float x){ return x > 0.f ? x : 0.2f*x; }
DEV float lrelu01(float x){ return x > 0.f ? x : 0.01f*x; }
DEV float fast_tanh(float x){
  float cx = fminf(fmaxf(x, -15.f), 15.f);
  float e = __expf(2.f*cx);
  return (e - 1.f) * __builtin_amdgcn_rcpf(e + 1.f);
}
DEV float wred_sum(float v){
  #pragma unroll
  for (int o = 32; o > 0; o >>= 1) v += __shfl_xor(v, o, 64);
  return v;
}
DEV float wred_max32(float v){
  #pragma unroll
  for (int o = 16; o > 0; o >>= 1) v = fmaxf(v, __shfl_xor(v, o, 64));
  return v;
}
DEV float wred_sum32(float v){
  #pragma unroll
  for (int o = 16; o > 0; o >>= 1) v += __shfl_xor(v, o, 64);
  return v;
}
// unpack 2 bf16 (packed in u32) -> float2
DEV v2f unpack2(u32 w){
  v2f r;
  r.x = __uint_as_float(w << 16);
  r.y = __uint_as_float(w & 0xffff0000u);
  return r;
}

constexpr int B_   = 8;
constexpr int P_   = 32;
constexpr int N0_  = 10000;
constexpr int NODES = B_ * N0_;      // 80000
constexpr int E_   = 160000;
constexpr int NE_  = E_ + N0_;       // 170000

// ---------------- merged setup ----------------
__global__ void __launch_bounds__(256) k_setup(int* __restrict__ zbase,
    const float* __restrict__ Wo, u16* __restrict__ WoT,
    const float* __restrict__ W1, const float* __restrict__ W2, u16* __restrict__ W12T,
    const float* __restrict__ as1, const float* __restrict__ ad1,
    float* __restrict__ va1s, float* __restrict__ va1d,
    const float* __restrict__ as2, const float* __restrict__ ad2,
    const float* __restrict__ bb1,
    float* __restrict__ v2ss, float* __restrict__ v2dd,
    float* __restrict__ cc, float* __restrict__ b12)
{
  __shared__ float l2s[272], l2d[272];
  int blk = blockIdx.x, tid = threadIdx.x;
  if (blk < 79){ int i = blk*256 + tid; if (i < 20080) zbase[i] = 0; return; }
  blk -= 79;
  if (blk < 180){           // WoT[n][k] (144x320), head split
    int i = blk*256 + tid; if (i >= 144*320) return;
    int n = i/320, k = i - n*320; float v = 0.f;
    if (n < 136){
      if (k < 136) v = Wo[(size_t)k*136 + n];
      else if (k >= 160 && k < 296) v = Wo[(size_t)(k-24)*136 + n];
    }
    WoT[i] = f2u(v); return;
  }
  blk -= 180;
  if (blk < 162){           // W12T[n][kk] (144x288) = (W1@W2)^T per head-block
    int i = blk*256 + tid; if (i >= 144*288) return;
    int n = i/288, kk = i - n*288; float v = 0.f;
    if (n < 136 && kk < 272){
      int hh = kk/136, k = kk - hh*136;
      for (int c = 0; c < 136; c++)
        v = fmaf(W1[(size_t)k*272 + hh*136 + c], W2[(size_t)(hh*136+c)*136 + n], v);
    }
    W12T[i] = f2u(v); return;
  }
  blk -= 162;
  if (blk < 2){             // va1 = W1 a1 (272)
    int t = blk*256 + tid; if (t >= 272) return;
    int hh = t/136, k = t - hh*136; float s = 0.f, d = 0.f;
    for (int c = 0; c < 136; c++){
      float w = W1[(size_t)k*272 + hh*136 + c];
      s = fmaf(w, as1[hh*136+c], s);
      d = fmaf(w, ad1[hh*136+c], d);
    }
    va1s[t] = s; va1d[t] = d; return;
  }
  blk -= 2;
  {                         // v2'' = W1@(W2 a2); cc = bb1·(W2 a2); b12 = bb1@W2
    for (int m = tid; m < 272; m += 256){
      float vs = 0.f, vd = 0.f;
      for (int n2 = 0; n2 < 136; n2++){
        float w2 = W2[(size_t)m*136 + n2];
        vs = fmaf(w2, as2[n2], vs);
        vd = fmaf(w2, ad2[n2], vd);
      }
      l2s[m] = vs; l2d[m] = vd;
    }
    __syncthreads();
    int t0 = blk*256 + tid;
    if (t0 < 272){
      int hh = t0/136, k = t0 - hh*136; float s = 0.f, d = 0.f;
      for (int c = 0; c < 136; c++){
        float w = W1[(size_t)k*272 + hh*136 + c];
        s = fmaf(w, l2s[hh*136+c], s);
        d = fmaf(w, l2d[hh*136+c], d);
      }
      v2ss[t0] = s; v2dd[t0] = d;
    }
    if (blk == 1){
      if (tid < 64){
        float s = 0.f, d = 0.f;
        for (int m = tid; m < 272; m += 64){
          s = fmaf(bb1[m], l2s[m], s);
          d = fmaf(bb1[m], l2d[m], d);
        }
        s = wred_sum(s); d = wred_sum(d);
        if (tid == 0){ cc[0] = s; cc[1] = d; }
      } else if (tid < 200){
        int n2 = tid - 64; float v = 0.f;
        for (int m = 0; m < 272; m++) v = fmaf(bb1[m], W2[(size_t)m*136 + n2], v);
        b12[n2] = v;
      }
    }
  }
}

// ---------------- backbone ----------------
DEV void load_convw(float* lw, const float* wl1, const float* wl2, const float* wp1,
                    const float* wp2, const float* wg, int tid, int nth){
  for (int i = tid; i < 384; i += nth){
    float v;
    if      (i < 24)  v = wl1[i];
    else if (i < 64)  v = wl2[i-24];
    else if (i < 88)  v = wp1[i-64];
    else if (i < 128) v = wp2[i-88];
    else              v = wg [i-128];
    lw[i] = v;
  }
}

template<int KS,int DIL,int T>
DEV void conv_stats(const float* xc, const float* wk, float& s, float& q){
  #pragma unroll
  for (int t = 0; t < T; t++){
    float v = 0.f;
    #pragma unroll
    for (int j = 0; j < KS; j++) v = fmaf(wk[j], xc[t + j*DIL], v);
    s += v; q = fmaf(v, v, q);
  }
}

__global__ void __launch_bounds__(256) k_bn_stats(
    const float* __restrict__ x,
    const float* __restrict__ wl1, const float* __restrict__ wl2,
    const float* __restrict__ wp1, const float* __restrict__ wp2,
    const float* __restrict__ wg,
    float* __restrict__ gsum, float* __restrict__ gsq)
{
  __shared__ float lw[384];
  __shared__ float lacc[80];
  const int tid = threadIdx.x;
  load_convw(lw, wl1, wl2, wp1, wp2, wg, tid, 256);
  if (tid < 80) lacc[tid] = 0.f;
  __syncthreads();

  const int lane = tid & 63, wv = tid >> 6;
  const int nodeLocal = (wv >> 1)*64 + lane;
  const int half = wv & 1;
  const int gid = blockIdx.x*128 + nodeLocal;
  float xc[P_];
  if (gid < NODES){
    int b = gid / N0_, n = gid - b*N0_;
    const float* xp = x + (size_t)b*P_*N0_ + n;
    #pragma unroll
    for (int p = 0; p < P_; p++) xc[p] = xp[(size_t)p*N0_];
  } else {
    #pragma unroll
    for (int p = 0; p < P_; p++) xc[p] = 0.f;
  }

  auto red = [&](int ch, float s, float q){
    #pragma unroll
    for (int o = 32; o > 0; o >>= 1){ s += __shfl_down(s,o,64); q += __shfl_down(q,o,64); }
    if (lane == 0){ atomicAdd(&lacc[ch], s); atomicAdd(&lacc[40+ch], q); }
  };

  if (half == 0){
    #pragma unroll
    for (int k = 0; k < 8; k++){ float s=0,q=0; conv_stats<3,1,30>(xc, lw      + k*3 , s,q); red(k,     s,q); }
    #pragma unroll
    for (int k = 0; k < 8; k++){ float s=0,q=0; conv_stats<5,1,28>(xc, lw + 24 + k*5 , s,q); red(8+k,   s,q); }
  } else {
    #pragma unroll
    for (int k = 0; k < 8; k++){ float s=0,q=0; conv_stats<3,2,28>(xc, lw + 64 + k*3 , s,q); red(16+k,  s,q); }
    #pragma unroll
    for (int k = 0; k < 8; k++){ float s=0,q=0; conv_stats<5,2,24>(xc, lw + 88 + k*5 , s,q); red(24+k,  s,q); }
    #pragma unroll
    for (int k = 0; k < 8; k++){ float s=0,q=0; conv_stats<32,1,1>(xc, lw + 128+ k*32, s,q); red(32+k,  s,q); }
  }

  __syncthreads();
  if (tid < 40)      atomicAdd(&gsum[tid],    lacc[tid]);
  else if (tid < 80) atomicAdd(&gsq [tid-40], lacc[tid]);
}

// count kernel with bn_fin folded in as the last block
__global__ void k_count(const int* __restrict__ ei, int* __restrict__ counts,
                        const float* __restrict__ gsum, const float* __restrict__ gsq,
                        float* __restrict__ sA, float* __restrict__ sB,
                        const float* g0, const float* g1, const float* g2, const float* g3, const float* g4,
                        const float* e0, const float* e1, const float* e2, const float* e3, const float* e4){
  if (blockIdx.x == 665){
    int t = threadIdx.x;
    if (t >= 40) return;
    int bi = t >> 3, k = t & 7;
    const int Ts[5] = {30,28,28,24,1};
    float cnt  = (float)NODES * (float)Ts[bi];
    float mean = gsum[t] / cnt;
    float var  = gsq[t] / cnt - mean*mean;
    const float* gp = bi==0?g0: bi==1?g1: bi==2?g2: bi==3?g3: g4;
    const float* ep = bi==0?e0: bi==1?e1: bi==2?e2: bi==3?e3: e4;
    float a = gp[k] * rsqrtf(fmaxf(var, 0.f) + 1e-5f);
    sA[t] = a;
    sB[t] = ep[k] - a*mean;
    return;
  }
  int e = blockIdx.x*blockDim.x + threadIdx.x;
  if (e >= NE_) return;
  int dst = (e < E_) ? ei[E_ + e] : (e - E_);
  atomicAdd(&counts[dst], 1);
}

// merged: block 0 = exclusive scan of counts -> offs; block 1 = degree counting-sort -> perm
__global__ void __launch_bounds__(1024) k_scan_perm(const int* __restrict__ counts,
                                                    int* __restrict__ offs,
                                                    int* __restrict__ perm){
  __shared__ int part[1024];
  __shared__ int hist[129];
  __shared__ int base[129];
  int t = threadIdx.x;
  if (blockIdx.x == 0){
    int loc[10]; int s = 0;
    #pragma unroll
    for (int i = 0; i < 10; i++){
      int idx = t*10 + i;
      int c = (idx < N0_) ? counts[idx] : 0;
      loc[i] = s; s += c;
    }
    part[t] = s;
    __syncthreads();
    for (int o = 1; o < 1024; o <<= 1){
      int v = (t >= o) ? part[t-o] : 0;
      __syncthreads();
      part[t] += v;
      __syncthreads();
    }
    int pre = (t == 0) ? 0 : part[t-1];
    #pragma unroll
    for (int i = 0; i < 10; i++){
      int idx = t*10 + i;
      if (idx < N0_) offs[idx] = pre + loc[i];
    }
    if (t == 0) offs[N0_] = part[1023];
  } else {
    if (t < 129) hist[t] = 0;
    __syncthreads();
    int dloc[10];
    #pragma unroll
    for (int i = 0; i < 10; i++){
      int idx = t*10 + i;
      if (idx < N0_){
        int d = min(counts[idx], 128);
        dloc[i] = d;
        atomicAdd(&hist[d], 1);
      }
    }
    __syncthreads();
    if (t == 0){
      int s = 0;
      for (int b = 0; b <= 128; b++){ base[b] = s; s += hist[b]; }
    }
    __syncthreads();
    #pragma unroll
    for (int i = 0; i < 10; i++){
      int idx = t*10 + i;
      if (idx < N0_){
        int pos = atomicAdd(&base[dloc[i]], 1);
        perm[pos] = idx;
      }
    }
  }
}

__global__ void k_scatter(const int* __restrict__ ei, const int* __restrict__ offs,
                          int* __restrict__ cursor, int* __restrict__ srcl){
  int e = blockIdx.x*blockDim.x + threadIdx.x;
  if (e >= NE_) return;
  int src, dst;
  if (e < E_){ src = ei[e]; dst = ei[E_ + e]; } else { src = dst = e - E_; }
  int pos = atomicAdd(&cursor[dst], 1);
  srcl[offs[dst] + pos] = src;
}

template<int KS,int DIL,int T>
DEV void conv_pool4(const float* xc, const float* wk, float A, float Bc, float* o4){
  float y[T];
  #pragma unroll
  for (int t = 0; t < T; t++){
    float v = 0.f;
    #pragma unroll
    for (int j = 0; j < KS; j++) v = fmaf(wk[j], xc[t + j*DIL], v);
    y[t] = fmaf(A, v, Bc);
  }
  #pragma unroll
  for (int i = 0; i < 4; i++){
    const int lo = (i*T)/4, hi = ((i+1)*T + 3)/4;
    float m = y[lo];
    #pragma unroll
    for (int t = 0; t < T; t++){ if (t > lo && t < hi) m = fmaxf(m, y[t]); }
    o4[i] = m;
  }
}

// feat [m][160] bf16 (tanh) + featL (lrelu01) + fused layer-1 attention dots.
// XCD-aligned grid: bb = blockIdx % CB (matches k_agg1's batch->XCD mapping),
// so batch-b feat rows are produced in the same XCD L2 that consumes them.
__global__ void __launch_bounds__(256) k_feat(
    const float* __restrict__ x,
    const float* __restrict__ wl1, const float* __restrict__ wl2,
    const float* __restrict__ wp1, const float* __restrict__ wp2,
    const float* __restrict__ wg,
    const float* __restrict__ sA, const float* __restrict__ sB,
    const float* __restrict__ va1s, const float* __restrict__ va1d,
    u16* __restrict__ feat, u16* __restrict__ featL,
    float* __restrict__ asrc1, float* __restrict__ adst1,
    int base, int cbN)
{
  __shared__ float lw[384];
  __shared__ float lA[40], lB[40];
  __shared__ float4 lv4[136];
  __shared__ float sdt[128][4];
  const int tid = threadIdx.x;
  load_convw(lw, wl1, wl2, wp1, wp2, wg, tid, 256);
  if (tid < 40){ lA[tid] = sA[tid]; lB[tid] = sB[tid]; }
  for (int i = tid; i < 136; i += 256)
    lv4[i] = make_float4(va1s[i], va1d[i], va1s[136+i], va1d[136+i]);
  __syncthreads();

  const int lane = tid & 63, wv = tid >> 6;
  const int nodeLocal = (wv >> 1)*64 + lane;     // 0..127
  const int half = wv & 1;                       // wave-uniform
  const int id = blockIdx.x;
  const int bb = id % cbN;
  const int rg = id / cbN;
  const int loc = rg*128 + nodeLocal;            // node within batch
  const bool act = loc < N0_;
  const int nodeIdx = bb*N0_ + (act ? loc : (N0_-1));
  const int gcl = base + nodeIdx;
  int b = gcl / N0_, n = gcl - b*N0_;
  float xc[P_];
  const float* xp = x + (size_t)b*P_*N0_ + n;
  #pragma unroll
  for (int p = 0; p < P_; p++) xc[p] = xp[(size_t)p*N0_];

  float dt[4] = {0.f,0.f,0.f,0.f};
  u32 pk[4], pkl[4];
  u16* orow  = feat  + (size_t)nodeIdx*160;
  u16* olrow = featL + (size_t)nodeIdx*160;
  auto emit = [&](int ch, float v){
    float t = fast_tanh(v);
    float4 vv = lv4[ch];
    dt[0] = fmaf(t, vv.x, dt[0]);
    dt[1] = fmaf(t, vv.y, dt[1]);
    dt[2] = fmaf(t, vv.z, dt[2]);
    dt[3] = fmaf(t, vv.w, dt[3]);
    u16 h  = f2u(t);
    u16 hl = f2u(lrelu01(t));
    int s = ch & 7;
    if ((s & 1) == 0){ pk[s>>1] = h;                pkl[s>>1] = hl; }
    else             { pk[s>>1] |= ((u32)h) << 16;  pkl[s>>1] |= ((u32)hl) << 16; }
    if (s == 7 && act){
      *(uint4*)(orow  + (ch - 7)) = make_uint4(pk[0],pk[1],pk[2],pk[3]);
      *(uint4*)(olrow + (ch - 7)) = make_uint4(pkl[0],pkl[1],pkl[2],pkl[3]);
    }
  };

  float o4[4];
  if (half == 0){
    #pragma unroll
    for (int k = 0; k < 8; k++){
      conv_pool4<3,1,30>(xc, lw + k*3, lA[k], lB[k], o4);
      #pragma unroll
      for (int i = 0; i < 4; i++) emit(k*4+i, o4[i]);
    }
    #pragma unroll
    for (int k = 0; k < 8; k++){
      conv_pool4<5,1,28>(xc, lw + 24 + k*5, lA[8+k], lB[8+k], o4);
      #pragma unroll
      for (int i = 0; i < 4; i++) emit(32 + k*4+i, o4[i]);
    }
  } else {
    #pragma unroll
    for (int k = 0; k < 8; k++){
      conv_pool4<3,2,28>(xc, lw + 64 + k*3, lA[16+k], lB[16+k], o4);
      #pragma unroll
      for (int i = 0; i < 4; i++) emit(64 + k*4+i, o4[i]);
    }
    #pragma unroll
    for (int k = 0; k < 8; k++){
      conv_pool4<5,2,24>(xc, lw + 88 + k*5, lA[24+k], lB[24+k], o4);
      #pragma unroll
      for (int i = 0; i < 4; i++) emit(96 + k*4+i, o4[i]);
    }
    #pragma unroll
    for (int k = 0; k < 8; k++){
      float v = 0.f;
      #pragma unroll
      for (int j = 0; j < 32; j++) v = fmaf(lw[128 + k*32 + j], xc[j], v);
      emit(128 + k, fmaf(lA[32+k], v, lB[32+k]));
    }
  }

  if (half == 1){
    sdt[nodeLocal][0] = dt[0]; sdt[nodeLocal][1] = dt[1];
    sdt[nodeLocal][2] = dt[2]; sdt[nodeLocal][3] = dt[3];
  }
  __syncthreads();
  if (half == 0 && act){
    asrc1[(size_t)nodeIdx*2]   = dt[0] + sdt[nodeLocal][0];
    asrc1[(size_t)nodeIdx*2+1] = dt[2] + sdt[nodeLocal][2];
    adst1[(size_t)nodeIdx*2]   = dt[1] + sdt[nodeLocal][1];
    adst1[(size_t)nodeIdx*2+1] = dt[3] + sdt[nodeLocal][3];
  }
}

// ---------------- MFMA GEMM: MT m-tiles (16 rows each) per wave ----------------
// XCD-aligned grid: bb = blockIdx % cbN selects the batch (same XCD as the
// producer k_agg1/k_agg2 blocks of that batch); rg walks rows within batch.
template<int MT,int KT1,int KT2,int NT,int EPI,int LR2>
__global__ void __launch_bounds__(256) k_mfma(
    const u16* __restrict__ A1, int sA1,
    const u16* __restrict__ A2, int sA2,
    const u16* __restrict__ BT, int sBT,
    u16* __restrict__ C, int sC, int nbase,
    const float* __restrict__ bias, int cbN,
    const float* __restrict__ w2v, const float* __restrict__ bo2p, float* __restrict__ fout)
{
  const int wv = threadIdx.x >> 6, lane = threadIdx.x & 63;
  const int quad = lane >> 4, l15 = lane & 15;
  const int id = blockIdx.x;
  const int bb = id % cbN;
  const int rg = id / cbN;
  const int rowb = bb*N0_;
  const int mbl = rg*(MT*64) + wv*(MT*16);     // local row base within batch
  int ar[MT];
  #pragma unroll
  for (int mt = 0; mt < MT; mt++) ar[mt] = rowb + min(mbl + mt*16 + l15, N0_-1);

  v4f acc[MT][NT];
  #pragma unroll
  for (int mt = 0; mt < MT; mt++)
    #pragma unroll
    for (int nt = 0; nt < NT; nt++)
      acc[mt][nt] = (v4f){0.f,0.f,0.f,0.f};

  for (int kt = 0; kt < KT1+KT2; kt++){
    const u16* ab; int sA, koff;
    if (KT2 == 0 || kt < KT1){ ab = A1; sA = sA1; koff = kt*32; }
    else { ab = A2; sA = sA2; koff = (kt-KT1)*32; }
    v8s a[MT];
    #pragma unroll
    for (int mt = 0; mt < MT; mt++)
      a[mt] = *(const v8s*)(ab + (size_t)ar[mt]*sA + koff + quad*8);
    if (KT2 > 0 && LR2 && kt >= KT1){
      #pragma unroll
      for (int mt = 0; mt < MT; mt++)
        #pragma unroll
        for (int j = 0; j < 8; j++){
          float f = u2f((u16)a[mt][j]);
          f = f > 0.f ? f : 0.01f*f;
          a[mt][j] = (short)f2u(f);
        }
    }
    const int kb = kt*32 + quad*8;
    #pragma unroll
    for (int nt = 0; nt < NT; nt++){
      v8s b = *(const v8s*)(BT + (size_t)(nbase + nt*16 + l15)*sBT + kb);
      #pragma unroll
      for (int mt = 0; mt < MT; mt++)
        acc[mt][nt] = __builtin_amdgcn_mfma_f32_16x16x32_bf16(a[mt], b, acc[mt][nt], 0, 0, 0);
    }
  }

  if (EPI == 2){
    const float bo2v = bo2p[0];
    #pragma unroll
    for (int mt = 0; mt < MT; mt++){
      float part[4] = {0.f,0.f,0.f,0.f};
      #pragma unroll
      for (int nt = 0; nt < NT; nt++){
        const int col = nt*16 + l15;
        float wv2 = (col < 136) ? w2v[col] : 0.f;
        float bv  = bias[min(col,135)];
        #pragma unroll
        for (int i = 0; i < 4; i++){
          float xv = lrelu01(acc[mt][nt][i] + bv);
          part[i] = fmaf(xv, wv2, part[i]);
        }
      }
      #pragma unroll
      for (int i = 0; i < 4; i++){
        float v = part[i];
        v += __shfl_xor(v, 1, 64);
        v += __shfl_xor(v, 2, 64);
        v += __shfl_xor(v, 4, 64);
        v += __shfl_xor(v, 8, 64);
        int rl = mbl + mt*16 + quad*4 + i;
        if (l15 == 0 && rl < N0_) fout[rowb + rl] = v + bo2v;
      }
    }
    return;
  }

  #pragma unroll
  for (int mt = 0; mt < MT; mt++){
    const int r0 = mbl + mt*16 + quad*4;
    #pragma unroll
    for (int nt = 0; nt < NT; nt++){
      const int col = nbase + nt*16 + l15;
      #pragma unroll
      for (int i = 0; i < 4; i++){
        int rl = r0 + i;
        if (rl < N0_){
          float xv = acc[mt][nt][i];
          if (EPI == 1){ xv += bias[min(col,135)]; xv = lrelu01(xv); }
          if (EPI == 3){ xv += bias[min(col,135)]; }
          C[(size_t)(rowb + rl)*sC + col] = f2u(xv);
        }
      }
    }
  }
}

// ---------------- layer-1 GAT aggregation ----------------
// two degree-paired dst per wave; per-edge meta {off,c0,c1} staged in LDS (uniform
// broadcast ds_read replaces 3x ds_bpermute); packed float2 accumulators (v_pk_fma_f32)
__global__ void __launch_bounds__(256) k_agg1(const u16* __restrict__ feat,
    const float* __restrict__ asrc, const float* __restrict__ adst,
    const int* __restrict__ offs, const int* __restrict__ srcl,
    const int* __restrict__ perm,
    u16* __restrict__ aggF,
    const float* __restrict__ v2s, const float* __restrict__ v2d,
    const float* __restrict__ cc,
    float* __restrict__ as_out, float* __restrict__ ad_out,
    int cbMask, int cbShift)
{
  __shared__ int4 smeta[4][2][32];
  const int tid = threadIdx.x;
  const int wv = tid >> 6, lane = tid & 63;
  const int half = lane >> 5, l32 = lane & 31;
  const int id = blockIdx.x;
  const int bb = id & cbMask;
  const int q = (id >> cbShift)*4 + wv;       // pair index
  const int dst = perm[2*q + half];
  const int nbase = bb*N0_;
  const int node = nbase + dst;
  const int start = offs[dst], end = offs[dst+1];
  const int ne = end - start;

  const float ad0 = adst[(size_t)node*2], ad1v = adst[(size_t)node*2+1];
  const char* featB = (const char*)feat;

  v2f m01h0 = {0.f,0.f}, m23h0 = {0.f,0.f};
  v2f m01h1 = {0.f,0.f}, m23h1 = {0.f,0.f};
  v2f r01h0 = {0.f,0.f}, r01h1 = {0.f,0.f};

  auto acc_one = [&](int4 mt){
    const u16* fp = (const u16*)(featB + mt.x);
    float c0 = __int_as_float(mt.y), c1 = __int_as_float(mt.z);
    const uint2 hv = *(const uint2*)(fp + 4*l32);
    v2f f01 = unpack2(hv.x), f23 = unpack2(hv.y);
    v2f cc0 = {c0,c0}, cc1 = {c1,c1};
    m01h0 = __builtin_elementwise_fma(f01, cc0, m01h0);
    m23h0 = __builtin_elementwise_fma(f23, cc0, m23h0);
    m01h1 = __builtin_elementwise_fma(f01, cc1, m01h1);
    m23h1 = __builtin_elementwise_fma(f23, cc1, m23h1);
    if (l32 < 4){
      const u32 hr = *(const u32*)(fp + 128 + 2*l32);
      v2f g01 = unpack2(hr);
      r01h0 = __builtin_elementwise_fma(g01, cc0, r01h0);
      r01h1 = __builtin_elementwise_fma(g01, cc1, r01h1);
    }
  };
  auto acc_four = [&](int4 ma, int4 mb, int4 mc, int4 md){
    const u16* p0 = (const u16*)(featB + ma.x);
    const u16* p1 = (const u16*)(featB + mb.x);
    const u16* p2 = (const u16*)(featB + mc.x);
    const u16* p3 = (const u16*)(featB + md.x);
    const uint2 v0 = *(const uint2*)(p0 + 4*l32);
    const uint2 v1 = *(const uint2*)(p1 + 4*l32);
    const uint2 v2 = *(const uint2*)(p2 + 4*l32);
    const uint2 v3 = *(const uint2*)(p3 + 4*l32);
    u32 q0, q1, q2, q3;
    if (l32 < 4){
      q0 = *(const u32*)(p0 + 128 + 2*l32);
      q1 = *(const u32*)(p1 + 128 + 2*l32);
      q2 = *(const u32*)(p2 + 128 + 2*l32);
      q3 = *(const u32*)(p3 + 128 + 2*l32);
    }
    v2f f01, f23, cA, cB;
    #define EDGE1(vv, qq, mm) \
      f01 = unpack2(vv.x); f23 = unpack2(vv.y); \
      cA = (v2f){__int_as_float(mm.y), __int_as_float(mm.y)}; \
      cB = (v2f){__int_as_float(mm.z), __int_as_float(mm.z)}; \
      m01h0 = __builtin_elementwise_fma(f01, cA, m01h0); \
      m23h0 = __builtin_elementwise_fma(f23, cA, m23h0); \
      m01h1 = __builtin_elementwise_fma(f01, cB, m01h1); \
      m23h1 = __builtin_elementwise_fma(f23, cB, m23h1); \
      if (l32 < 4){ \
        v2f g01 = unpack2(qq); \
        r01h0 = __builtin_elementwise_fma(g01, cA, r01h0); \
        r01h1 = __builtin_elementwise_fma(g01, cB, r01h1); \
      }
    EDGE1(v0, q0, ma)
    EDGE1(v1, q1, mb)
    EDGE1(v2, q2, mc)
    EDGE1(v3, q3, md)
    #undef EDGE1
  };
  auto run_chunk = [&](int cnt){
    const int4* mp = &smeta[wv][half][0];
    int j = 0;
    for (; j + 3 < cnt; j += 4)
      acc_four(mp[j], mp[j+1], mp[j+2], mp[j+3]);
    for (; j < cnt; j++)
      acc_one(mp[j]);
  };

  if (ne <= 32){
    const bool has = l32 < ne;
    const int sn = nbase + (has ? srcl[start + l32] : 0);
    const int offL = sn * 320;
    float al0 = has ? lrelu02(asrc[(size_t)sn*2]   + ad0)  : -1e30f;
    float al1 = has ? lrelu02(asrc[(size_t)sn*2+1] + ad1v) : -1e30f;
    float mm = wred_max32(al0);
    float p0 = has ? __expf(al0 - mm) : 0.f;
    float c0 = p0 * (1.f/(wred_sum32(p0) + 1e-16f));
    mm = wred_max32(al1);
    float p1 = has ? __expf(al1 - mm) : 0.f;
    float c1 = p1 * (1.f/(wred_sum32(p1) + 1e-16f));
    if (has)
      smeta[wv][half][l32] = make_int4(offL, __float_as_int(c0), __float_as_int(c1), 0);
    asm volatile("s_waitcnt lgkmcnt(0)" ::: "memory");
    run_chunk(ne);
  } else {
    float lm0 = -1e30f, lm1 = -1e30f;
    for (int e = start + l32; e < end; e += 32){
      int sn = nbase + srcl[e];
      lm0 = fmaxf(lm0, lrelu02(asrc[(size_t)sn*2]   + ad0));
      lm1 = fmaxf(lm1, lrelu02(asrc[(size_t)sn*2+1] + ad1v));
    }
    float m0 = wred_max32(lm0), m1 = wred_max32(lm1);
    float ls0 = 0.f, ls1 = 0.f;
    for (int e = start + l32; e < end; e += 32){
      int sn = nbase + srcl[e];
      ls0 += __expf(lrelu02(asrc[(size_t)sn*2]   + ad0)  - m0);
      ls1 += __expf(lrelu02(asrc[(size_t)sn*2+1] + ad1v) - m1);
    }
    float si0 = 1.f/(wred_sum32(ls0) + 1e-16f);
    float si1 = 1.f/(wred_sum32(ls1) + 1e-16f);
    for (int cs = start; cs < end; cs += 32){
      int cnt = min(32, end - cs);
      bool has = l32 < cnt;
      int sn = nbase + (has ? srcl[cs + l32] : 0);
      int offL = sn * 320;
      float c0 = 0.f, c1 = 0.f;
      if (has){
        c0 = __expf(lrelu02(asrc[(size_t)sn*2]   + ad0)  - m0) * si0;
        c1 = __expf(lrelu02(asrc[(size_t)sn*2+1] + ad1v) - m1) * si1;
      }
      if (has)
        smeta[wv][half][l32] = make_int4(offL, __float_as_int(c0), __float_as_int(c1), 0);
      asm volatile("s_waitcnt lgkmcnt(0)" ::: "memory");
      run_chunk(cnt);
    }
  }

  u16* outp = aggF + (size_t)node*288;
  {
    ushort4 s0; s0.x=f2u(m01h0.x); s0.y=f2u(m01h0.y); s0.z=f2u(m23h0.x); s0.w=f2u(m23h0.y);
    *(ushort4*)(outp + 4*l32) = s0;
    ushort4 s1; s1.x=f2u(m01h1.x); s1.y=f2u(m01h1.y); s1.z=f2u(m23h1.x); s1.w=f2u(m23h1.y);
    *(ushort4*)(outp + 136 + 4*l32) = s1;
    if (l32 < 4){
      ushort2 t0; t0.x=f2u(r01h0.x); t0.y=f2u(r01h0.y);
      *(ushort2*)(outp + 128 + 2*l32) = t0;
      ushort2 t1; t1.x=f2u(r01h1.x); t1.y=f2u(r01h1.y);
      *(ushort2*)(outp + 136 + 128 + 2*l32) = t1;
    }
  }
  {
    int c = 4*l32;
    float s = m01h0.x*v2s[c] + m01h0.y*v2s[c+1] + m23h0.x*v2s[c+2] + m23h0.y*v2s[c+3]
            + m01h1.x*v2s[136+c] + m01h1.y*v2s[136+c+1] + m23h1.x*v2s[136+c+2] + m23h1.y*v2s[136+c+3];
    float d = m01h0.x*v2d[c] + m01h0.y*v2d[c+1] + m23h0.x*v2d[c+2] + m23h0.y*v2d[c+3]
            + m01h1.x*v2d[136+c] + m01h1.y*v2d[136+c+1] + m23h1.x*v2d[136+c+2] + m23h1.y*v2d[136+c+3];
    if (l32 < 4){
      int cr = 128 + 2*l32;
      s += r01h0.x*v2s[cr] + r01h0.y*v2s[cr+1] + r01h1.x*v2s[136+cr] + r01h1.y*v2s[136+cr+1];
      d += r01h0.x*v2d[cr] + r01h0.y*v2d[cr+1] + r01h1.x*v2d[136+cr] + r01h1.y*v2d[136+cr+1];
    }
    s = wred_sum32(s); d = wred_sum32(d);
    if (l32 == 0){ as_out[node] = s + cc[0]; ad_out[node] = d + cc[1]; }
  }
}

// ---------------- layer-2 GAT aggregation (H=1) ----------------
__global__ void __launch_bounds__(256) k_agg2(const u16* __restrict__ h, int sh,
    const float* __restrict__ asrc, const float* __restrict__ adst,
    const int* __restrict__ offs, const int* __restrict__ srcl,
    const int* __restrict__ perm,
    const float* __restrict__ bias, u16* __restrict__ outp0, int so,
    int cbMask, int cbShift)
{
  __shared__ int2 smeta[4][2][32];
  const int tid = threadIdx.x;
  const int wv = tid >> 6, lane = tid & 63;
  const int half = lane >> 5, l32 = lane & 31;
  const int id = blockIdx.x;
  const int bb = id & cbMask;
  const int q = (id >> cbShift)*4 + wv;
  const int dst = perm[2*q + half];
  const int nbase = bb*N0_;
  const int node = nbase + dst;
  const int start = offs[dst], end = offs[dst+1];
  const int ne = end - start;
  const int bstride = 2*sh;

  const float adh = adst[node];
  const char* hB = (const char*)h;

  v2f a01 = {0.f,0.f}, a23 = {0.f,0.f}, r01 = {0.f,0.f};

  auto acc_one = [&](int2 mt){
    const u16* hp = (const u16*)(hB + mt.x);
    float c0 = __int_as_float(mt.y);
    const uint2 hv = *(const uint2*)(hp + 4*l32);
    v2f cc0 = {c0,c0};
    a01 = __builtin_elementwise_fma(unpack2(hv.x), cc0, a01);
    a23 = __builtin_elementwise_fma(unpack2(hv.y), cc0, a23);
    if (l32 < 4){
      const u32 hr = *(const u32*)(hp + 128 + 2*l32);
      r01 = __builtin_elementwise_fma(unpack2(hr), cc0, r01);
    }
  };
  auto acc_four = [&](int2 ma, int2 mb, int2 mc, int2 md){
    const u16* p0 = (const u16*)(hB + ma.x);
    const u16* p1 = (const u16*)(hB + mb.x);
    const u16* p2 = (const u16*)(hB + mc.x);
    const u16* p3 = (const u16*)(hB + md.x);
    const uint2 v0 = *(const uint2*)(p0 + 4*l32);
    const uint2 v1 = *(const uint2*)(p1 + 4*l32);
    const uint2 v2 = *(const uint2*)(p2 + 4*l32);
    const uint2 v3 = *(const uint2*)(p3 + 4*l32);
    u32 q0, q1, q2, q3;
    if (l32 < 4){
      q0 = *(const u32*)(p0 + 128 + 2*l32);
      q1 = *(const u32*)(p1 + 128 + 2*l32);
      q2 = *(const u32*)(p2 + 128 + 2*l32);
      q3 = *(const u32*)(p3 + 128 + 2*l32);
    }
    v2f cc;
    #define EDGE2(vv, qq, mm) \
      cc = (v2f){__int_as_float(mm.y), __int_as_float(mm.y)}; \
      a01 = __builtin_elementwise_fma(unpack2(vv.x), cc, a01); \
      a23 = __builtin_elementwise_fma(unpack2(vv.y), cc, a23); \
      if (l32 < 4) r01 = __builtin_elementwise_fma(unpack2(qq), cc, r01);
    EDGE2(v0, q0, ma)
    EDGE2(v1, q1, mb)
    EDGE2(v2, q2, mc)
    EDGE2(v3, q3, md)
    #undef EDGE2
  };
  auto run_chunk = [&](int cnt){
    const int2* mp = &smeta[wv][half][0];
    int j = 0;
    for (; j + 3 < cnt; j += 4)
      acc_four(mp[j], mp[j+1], mp[j+2], mp[j+3]);
    for (; j < cnt; j++)
      acc_one(mp[j]);
  };

  if (ne <= 32){
    const bool has = l32 < ne;
    const int sn = nbase + (has ? srcl[start + l32] : 0);
    const int offL = sn * bstride;
    float al = has ? lrelu02(asrc[sn] + adh) : -1e30f;
    float m = wred_max32(al);
    float p = has ? __expf(al - m) : 0.f;
    float c0 = p * (1.f/(wred_sum32(p) + 1e-16f));
    if (has)
      smeta[wv][half][l32] = make_int2(offL, __float_as_int(c0));
    asm volatile("s_waitcnt lgkmcnt(0)" ::: "memory");
    run_chunk(ne);
  } else {
    float lm = -1e30f;
    for (int e = start + l32; e < end; e += 32){
      int sn = nbase + srcl[e];
      lm = fmaxf(lm, lrelu02(asrc[sn] + adh));
    }
    float m = wred_max32(lm);
    float ls = 0.f;
    for (int e = start + l32; e < end; e += 32){
      int sn = nbase + srcl[e];
      ls += __expf(lrelu02(asrc[sn] + adh) - m);
    }
    float si = 1.f/(wred_sum32(ls) + 1e-16f);
    for (int cs = start; cs < end; cs += 32){
      int cnt = min(32, end - cs);
      bool has = l32 < cnt;
      int sn = nbase + (has ? srcl[cs + l32] : 0);
      int offL = sn * bstride;
      float c0 = has ? __expf(lrelu02(asrc[sn] + adh) - m) * si : 0.f;
      if (has)
        smeta[wv][half][l32] = make_int2(offL, __float_as_int(c0));
      asm volatile("s_waitcnt lgkmcnt(0)" ::: "memory");
      run_chunk(cnt);
    }
  }

  u16* outp = outp0 + (size_t)node*so;
  {
    int c = 4*l32;
    ushort4 st;
    st.x = f2u(lrelu01(a01.x + bias[c]));
    st.y = f2u(lrelu01(a01.y + bias[c+1]));
    st.z = f2u(lrelu01(a23.x + bias[c+2]));
    st.w = f2u(lrelu01(a23.y + bias[c+3]));
    *(ushort4*)(outp + c) = st;
    if (l32 < 4){
      int cr = 128 + 2*l32;
      ushort2 sr;
      sr.x = f2u(lrelu01(r01.x + bias[cr]));
      sr.y = f2u(lrelu01(r01.y + bias[cr+1]));
      *(ushort2*)(outp + cr) = sr;
    }
  }
}

// ---------------- launch ----------------
extern "C" void kernel_launch(void* const* d_in, const int* in_sizes, int n_in,
                              void* d_out, int out_size, void* d_ws, size_t ws_size,
                              hipStream_t stream)
{
  (void)in_sizes; (void)n_in; (void)out_size;
  const float* x    = (const float*)d_in[0];
  const float* wl1  = (const float*)d_in[1];
  const float* gl1  = (const float*)d_in[3];
  const float* bel1 = (const float*)d_in[4];
  const float* wl2  = (const float*)d_in[5];
  const float* gl2  = (const float*)d_in[7];
  const float* bel2 = (const float*)d_in[8];
  const float* wp1  = (const float*)d_in[9];
  const float* gp1  = (const float*)d_in[11];
  const float* bep1 = (const float*)d_in[12];
  const float* wp2  = (const float*)d_in[13];
  const float* gp2  = (const float*)d_in[15];
  const float* bep2 = (const float*)d_in[16];
  const float* wg   = (const float*)d_in[17];
  const float* gg   = (const float*)d_in[19];
  const float* beg  = (const float*)d_in[20];
  const float* W1   = (const float*)d_in[21];
  const float* as1  = (const float*)d_in[22];
  const float* ad1  = (const float*)d_in[23];
  const float* bb1  = (const float*)d_in[24];
  const float* W2   = (const float*)d_in[25];
  const float* as2  = (const float*)d_in[26];
  const float* ad2  = (const float*)d_in[27];
  const float* bb2  = (const float*)d_in[28];
  const float* Wo   = (const float*)d_in[29];
  const float* bo   = (const float*)d_in[30];
  const float* Wo2  = (const float*)d_in[31];
  const float* bo2  = (const float*)d_in[32];
  const int*   ei   = (const int*)d_in[33];

  const size_t STATIC_BYTES = 1250000;
  int nc = 1;
  while (nc < 8 && STATIC_BYTES + (size_t)1880*(NODES/nc) > ws_size) nc <<= 1;
  const int CB = B_/nc, CN = CB*N0_;
  int cbShift = 0; while ((1 << cbShift) < CB) cbShift++;
  const int cbMask = CB - 1;

  char* wsb = (char*)d_ws; size_t off = 0;
  auto alloc = [&](size_t nbytes)->void*{
    void* p = wsb + off; off = (off + nbytes + 255) & ~(size_t)255; return p;
  };
  int*   zbase  = (int*)  alloc(20080*sizeof(int));
  float* gsum   = (float*)zbase;
  float* gsq    = gsum + 40;
  int*   counts = zbase + 80;
  int*   cursor = counts + 10000;
  float* sA     = (float*)alloc(40*sizeof(float));
  float* sB     = (float*)alloc(40*sizeof(float));
  int*   offs   = (int*)  alloc(10001*sizeof(int));
  int*   srcl   = (int*)  alloc((size_t)NE_*sizeof(int));
  int*   perm   = (int*)  alloc((size_t)N0_*sizeof(int));
  u16*   W12T   = (u16*)  alloc((size_t)144*288*2);
  u16*   WoT    = (u16*)  alloc((size_t)144*320*2);
  float* va1s   = (float*)alloc(272*sizeof(float));
  float* va1d   = (float*)alloc(272*sizeof(float));
  float* v2ss   = (float*)alloc(272*sizeof(float));
  float* v2dd   = (float*)alloc(272*sizeof(float));
  float* ccv    = (float*)alloc(2*sizeof(float));
  float* b12    = (float*)alloc(136*sizeof(float));
  u16*   feat   = (u16*)  alloc((size_t)CN*160*2);
  u16*   featL  = (u16*)  alloc((size_t)CN*160*2);
  u16*   aggF   = (u16*)  alloc((size_t)CN*288*2);
  u16*   h2     = (u16*)  alloc((size_t)CN*144*2);
  u16*   g2l    = (u16*)  alloc((size_t)CN*160*2);
  float* asrc1  = (float*)alloc((size_t)CN*2*sizeof(float));
  float* adst1  = (float*)alloc((size_t)CN*2*sizeof(float));
  float* asrc2  = (float*)alloc((size_t)CN*sizeof(float));
  float* adst2  = (float*)alloc((size_t)CN*sizeof(float));

  k_setup<<<425,256,0,stream>>>(zbase, Wo, WoT, W1, W2, W12T,
                                as1, ad1, va1s, va1d, as2, ad2, bb1,
                                v2ss, v2dd, ccv, b12);

  k_bn_stats<<<625,256,0,stream>>>(x, wl1,wl2,wp1,wp2,wg, gsum, gsq);

  k_count  <<<666,256,0,stream>>>(ei, counts, gsum, gsq, sA, sB,
                                  gl1,gl2,gp1,gp2,gg, bel1,bel2,bep1,bep2,beg);
  k_scan_perm<<<2,1024,0,stream>>>(counts, offs, perm);
  k_scatter<<<665,256,0,stream>>>(ei, offs, cursor, srcl);

  const int rpb  = (N0_ + 127)/128;   // 79 row-blocks per batch (128 rows each)
  const int gxf  = CB * rpb;          // XCD-aligned grids
  const int aggB = 1250*CB;
  for (int c = 0; c < nc; c++){
    const int base = c*CN;

    k_feat<<<gxf,256,0,stream>>>(x, wl1,wl2,wp1,wp2,wg, sA, sB, va1s, va1d,
                                 feat, featL, asrc1, adst1, base, CB);

    k_agg1<<<aggB,256,0,stream>>>(feat, asrc1, adst1, offs, srcl, perm, aggF,
                                  v2ss, v2dd, ccv, asrc2, adst2, cbMask, cbShift);

    k_mfma<2,9,0,9,3,0><<<gxf,256,0,stream>>>(aggF,288, (const u16*)0,0, W12T,288, h2,144, 0, b12, CB,
                                              (const float*)0,(const float*)0,(float*)0);

    k_agg2<<<aggB,256,0,stream>>>(h2,144, asrc2, adst2, offs, srcl, perm, bb2, g2l,160,
                                  cbMask, cbShift);

    k_mfma<2,5,5,9,2,0><<<gxf,256,0,stream>>>(g2l,160, featL,160, WoT,320, (u16*)0,0, 0, bo, CB,
                                              Wo2, bo2, (float*)d_out + base);
  }
}

// Round 5
// 408.597 us; speedup vs baseline: 1.1515x; 1.1515x over previous
//
#include <hip/hip_runtime.h>
#include <hip/hip_bf16.h>
#include <math.h>

typedef unsigned short u16;
typedef unsigned int   u32;
typedef short v8s __attribute__((ext_vector_type(8)));
typedef float v4f __attribute__((ext_vector_type(4)));
typedef float v2f __attribute__((ext_vector_type(2)));
#define DEV static __device__ __forceinline__

DEV float u2f(u16 u){ union{u32 i; float f;} v; v.i = ((u32)u)<<16; return v.f; }
DEV u16   f2u(float f){ union{float ff; u32 i;} v; v.ff = f; u32 r = v.i + 0x7fffu + ((v.i>>16)&1u); return (u16)(r>>16); }
DEV float lrelu02(float x){ return x > 0.f ? x : 0.2f*x; }
DEV float lrelu01(float x){ return x > 0.f ? x : 0.01f*x; }
DEV float fast_tanh(float x){
  float cx = fminf(fmaxf(x, -15.f), 15.f);
  float e = __expf(2.f*cx);
  return (e - 1.f) * __builtin_amdgcn_rcpf(e + 1.f);
}
DEV float wred_sum(float v){
  #pragma unroll
  for (int o = 32; o > 0; o >>= 1) v += __shfl_xor(v, o, 64);
  return v;
}
DEV float wred_max32(float v){
  #pragma unroll
  for (int o = 16; o > 0; o >>= 1) v = fmaxf(v, __shfl_xor(v, o, 64));
  return v;
}
DEV float wred_sum32(float v){
  #pragma unroll
  for (int o = 16; o > 0; o >>= 1) v += __shfl_xor(v, o, 64);
  return v;
}
// unpack 2 bf16 (packed in u32) -> float2
DEV v2f unpack2(u32 w){
  v2f r;
  r.x = __uint_as_float(w << 16);
  r.y = __uint_as_float(w & 0xffff0000u);
  return r;
}

constexpr int B_   = 8;
constexpr int P_   = 32;
constexpr int N0_  = 10000;
constexpr int NODES = B_ * N0_;      // 80000
constexpr int E_   = 160000;
constexpr int NE_  = E_ + N0_;       // 170000

// ---------------- conv weight staging ----------------
DEV void load_convw(float* lw, const float* wl1, const float* wl2, const float* wp1,
                    const float* wp2, const float* wg, int tid, int nth){
  for (int i = tid; i < 384; i += nth){
    float v;
    if      (i < 24)  v = wl1[i];
    else if (i < 64)  v = wl2[i-24];
    else if (i < 88)  v = wp1[i-64];
    else if (i < 128) v = wp2[i-88];
    else              v = wg [i-128];
    lw[i] = v;
  }
}

template<int KS,int DIL,int T>
DEV void conv_stats(const float* xc, const float* wk, float& s, float& q){
  #pragma unroll
  for (int t = 0; t < T; t++){
    float v = 0.f;
    #pragma unroll
    for (int j = 0; j < KS; j++) v = fmaf(wk[j], xc[t + j*DIL], v);
    s += v; q = fmaf(v, v, q);
  }
}

// ---------------- K1: setup + bn_stats + edge-count histogram (one launch) ----
// blocks [0,180): WoT; [180,342): W12T; [342,344): va1; [344,346): v2''/cc/b12;
// [346,971): bn_stats; [971,1636): count histogram.
__global__ void __launch_bounds__(256) k_mega1(
    const float* __restrict__ Wo, u16* __restrict__ WoT,
    const float* __restrict__ W1, const float* __restrict__ W2, u16* __restrict__ W12T,
    const float* __restrict__ as1, const float* __restrict__ ad1,
    float* __restrict__ va1s, float* __restrict__ va1d,
    const float* __restrict__ as2, const float* __restrict__ ad2,
    const float* __restrict__ bb1,
    float* __restrict__ v2ss, float* __restrict__ v2dd,
    float* __restrict__ cc, float* __restrict__ b12,
    const float* __restrict__ x,
    const float* __restrict__ wl1, const float* __restrict__ wl2,
    const float* __restrict__ wp1, const float* __restrict__ wp2,
    const float* __restrict__ wg,
    float* __restrict__ gsum, float* __restrict__ gsq,
    const int* __restrict__ ei, int* __restrict__ counts)
{
  __shared__ float smem[544];
  int blk = blockIdx.x, tid = threadIdx.x;
  if (blk < 180){           // WoT[n][k] (144x320), head split
    int i = blk*256 + tid; if (i >= 144*320) return;
    int n = i/320, k = i - n*320; float v = 0.f;
    if (n < 136){
      if (k < 136) v = Wo[(size_t)k*136 + n];
      else if (k >= 160 && k < 296) v = Wo[(size_t)(k-24)*136 + n];
    }
    WoT[i] = f2u(v); return;
  }
  blk -= 180;
  if (blk < 162){           // W12T[n][kk] (144x288) = (W1@W2)^T per head-block
    int i = blk*256 + tid; if (i >= 144*288) return;
    int n = i/288, kk = i - n*288; float v = 0.f;
    if (n < 136 && kk < 272){
      int hh = kk/136, k = kk - hh*136;
      for (int c = 0; c < 136; c++)
        v = fmaf(W1[(size_t)k*272 + hh*136 + c], W2[(size_t)(hh*136+c)*136 + n], v);
    }
    W12T[i] = f2u(v); return;
  }
  blk -= 162;
  if (blk < 2){             // va1 = W1 a1 (272)
    int t = blk*256 + tid; if (t >= 272) return;
    int hh = t/136, k = t - hh*136; float s = 0.f, d = 0.f;
    for (int c = 0; c < 136; c++){
      float w = W1[(size_t)k*272 + hh*136 + c];
      s = fmaf(w, as1[hh*136+c], s);
      d = fmaf(w, ad1[hh*136+c], d);
    }
    va1s[t] = s; va1d[t] = d; return;
  }
  blk -= 2;
  if (blk < 2){             // v2'' = W1@(W2 a2); cc = bb1·(W2 a2); b12 = bb1@W2
    float* l2s = smem; float* l2d = smem + 272;
    for (int m = tid; m < 272; m += 256){
      float vs = 0.f, vd = 0.f;
      for (int n2 = 0; n2 < 136; n2++){
        float w2 = W2[(size_t)m*136 + n2];
        vs = fmaf(w2, as2[n2], vs);
        vd = fmaf(w2, ad2[n2], vd);
      }
      l2s[m] = vs; l2d[m] = vd;
    }
    __syncthreads();
    int t0 = blk*256 + tid;
    if (t0 < 272){
      int hh = t0/136, k = t0 - hh*136; float s = 0.f, d = 0.f;
      for (int c = 0; c < 136; c++){
        float w = W1[(size_t)k*272 + hh*136 + c];
        s = fmaf(w, l2s[hh*136+c], s);
        d = fmaf(w, l2d[hh*136+c], d);
      }
      v2ss[t0] = s; v2dd[t0] = d;
    }
    if (blk == 1){
      if (tid < 64){
        float s = 0.f, d = 0.f;
        for (int m = tid; m < 272; m += 64){
          s = fmaf(bb1[m], l2s[m], s);
          d = fmaf(bb1[m], l2d[m], d);
        }
        s = wred_sum(s); d = wred_sum(d);
        if (tid == 0){ cc[0] = s; cc[1] = d; }
      } else if (tid < 200){
        int n2 = tid - 64; float v = 0.f;
        for (int m = 0; m < 272; m++) v = fmaf(bb1[m], W2[(size_t)m*136 + n2], v);
        b12[n2] = v;
      }
    }
    return;
  }
  blk -= 2;
  if (blk < 625){           // bn_stats
    float* lw = smem; float* lacc = smem + 384;
    load_convw(lw, wl1, wl2, wp1, wp2, wg, tid, 256);
    if (tid < 80) lacc[tid] = 0.f;
    __syncthreads();

    const int lane = tid & 63, wv = tid >> 6;
    const int nodeLocal = (wv >> 1)*64 + lane;
    const int half = wv & 1;
    const int gid = blk*128 + nodeLocal;
    float xc[P_];
    if (gid < NODES){
      int b = gid / N0_, n = gid - b*N0_;
      const float* xp = x + (size_t)b*P_*N0_ + n;
      #pragma unroll
      for (int p = 0; p < P_; p++) xc[p] = xp[(size_t)p*N0_];
    } else {
      #pragma unroll
      for (int p = 0; p < P_; p++) xc[p] = 0.f;
    }

    auto red = [&](int ch, float s, float q){
      #pragma unroll
      for (int o = 32; o > 0; o >>= 1){ s += __shfl_down(s,o,64); q += __shfl_down(q,o,64); }
      if (lane == 0){ atomicAdd(&lacc[ch], s); atomicAdd(&lacc[40+ch], q); }
    };

    if (half == 0){
      #pragma unroll
      for (int k = 0; k < 8; k++){ float s=0,q=0; conv_stats<3,1,30>(xc, lw      + k*3 , s,q); red(k,     s,q); }
      #pragma unroll
      for (int k = 0; k < 8; k++){ float s=0,q=0; conv_stats<5,1,28>(xc, lw + 24 + k*5 , s,q); red(8+k,   s,q); }
    } else {
      #pragma unroll
      for (int k = 0; k < 8; k++){ float s=0,q=0; conv_stats<3,2,28>(xc, lw + 64 + k*3 , s,q); red(16+k,  s,q); }
      #pragma unroll
      for (int k = 0; k < 8; k++){ float s=0,q=0; conv_stats<5,2,24>(xc, lw + 88 + k*5 , s,q); red(24+k,  s,q); }
      #pragma unroll
      for (int k = 0; k < 8; k++){ float s=0,q=0; conv_stats<32,1,1>(xc, lw + 128+ k*32, s,q); red(32+k,  s,q); }
    }

    __syncthreads();
    if (tid < 40)      atomicAdd(&gsum[tid],    lacc[tid]);
    else if (tid < 80) atomicAdd(&gsq [tid-40], lacc[tid]);
    return;
  }
  blk -= 625;
  {                         // edge-count histogram (665 blocks)
    int e = blk*256 + tid;
    if (e >= NE_) return;
    int dst = (e < E_) ? ei[E_ + e] : (e - E_);
    atomicAdd(&counts[dst], 1);
  }
}

// ---------------- K2: bn_fin + scan + perm (3 blocks, one launch) -------------
__global__ void __launch_bounds__(1024) k_mega2(
    const int* __restrict__ counts, int* __restrict__ offs, int* __restrict__ perm,
    const float* __restrict__ gsum, const float* __restrict__ gsq,
    float* __restrict__ sA, float* __restrict__ sB,
    const float* g0, const float* g1, const float* g2, const float* g3, const float* g4,
    const float* e0, const float* e1, const float* e2, const float* e3, const float* e4)
{
  __shared__ int part[1024];
  __shared__ int hist[129];
  __shared__ int base[129];
  int t = threadIdx.x;
  if (blockIdx.x == 0){     // bn_fin
    if (t >= 40) return;
    int bi = t >> 3, k = t & 7;
    const int Ts[5] = {30,28,28,24,1};
    float cnt  = (float)NODES * (float)Ts[bi];
    float mean = gsum[t] / cnt;
    float var  = gsq[t] / cnt - mean*mean;
    const float* gp = bi==0?g0: bi==1?g1: bi==2?g2: bi==3?g3: g4;
    const float* ep = bi==0?e0: bi==1?e1: bi==2?e2: bi==3?e3: e4;
    float a = gp[k] * rsqrtf(fmaxf(var, 0.f) + 1e-5f);
    sA[t] = a;
    sB[t] = ep[k] - a*mean;
    return;
  }
  if (blockIdx.x == 1){     // exclusive scan -> offs
    int loc[10]; int s = 0;
    #pragma unroll
    for (int i = 0; i < 10; i++){
      int idx = t*10 + i;
      int c = (idx < N0_) ? counts[idx] : 0;
      loc[i] = s; s += c;
    }
    part[t] = s;
    __syncthreads();
    for (int o = 1; o < 1024; o <<= 1){
      int v = (t >= o) ? part[t-o] : 0;
      __syncthreads();
      part[t] += v;
      __syncthreads();
    }
    int pre = (t == 0) ? 0 : part[t-1];
    #pragma unroll
    for (int i = 0; i < 10; i++){
      int idx = t*10 + i;
      if (idx < N0_) offs[idx] = pre + loc[i];
    }
    if (t == 0) offs[N0_] = part[1023];
  } else {                  // degree counting-sort -> perm
    if (t < 129) hist[t] = 0;
    __syncthreads();
    int dloc[10];
    #pragma unroll
    for (int i = 0; i < 10; i++){
      int idx = t*10 + i;
      if (idx < N0_){
        int d = min(counts[idx], 128);
        dloc[i] = d;
        atomicAdd(&hist[d], 1);
      }
    }
    __syncthreads();
    if (t == 0){
      int s = 0;
      for (int b = 0; b <= 128; b++){ base[b] = s; s += hist[b]; }
    }
    __syncthreads();
    #pragma unroll
    for (int i = 0; i < 10; i++){
      int idx = t*10 + i;
      if (idx < N0_){
        int pos = atomicAdd(&base[dloc[i]], 1);
        perm[pos] = idx;
      }
    }
  }
}

template<int KS,int DIL,int T>
DEV void conv_pool4(const float* xc, const float* wk, float A, float Bc, float* o4){
  float y[T];
  #pragma unroll
  for (int t = 0; t < T; t++){
    float v = 0.f;
    #pragma unroll
    for (int j = 0; j < KS; j++) v = fmaf(wk[j], xc[t + j*DIL], v);
    y[t] = fmaf(A, v, Bc);
  }
  #pragma unroll
  for (int i = 0; i < 4; i++){
    const int lo = (i*T)/4, hi = ((i+1)*T + 3)/4;
    float m = y[lo];
    #pragma unroll
    for (int t = 0; t < T; t++){ if (t > lo && t < hi) m = fmaxf(m, y[t]); }
    o4[i] = m;
  }
}

// ---------------- K3: feat (tanh bf16 + attn dots) + edge scatter -------------
// blocks [0,featBlocks): feat; [featBlocks, featBlocks+665): scatter (c==0 only).
__global__ void __launch_bounds__(256) k_feat_sc(
    const float* __restrict__ x,
    const float* __restrict__ wl1, const float* __restrict__ wl2,
    const float* __restrict__ wp1, const float* __restrict__ wp2,
    const float* __restrict__ wg,
    const float* __restrict__ sA, const float* __restrict__ sB,
    const float* __restrict__ va1s, const float* __restrict__ va1d,
    u16* __restrict__ feat,
    float* __restrict__ asrc1, float* __restrict__ adst1,
    int base, int m, int featBlocks,
    const int* __restrict__ ei, const int* __restrict__ offs,
    int* __restrict__ cursor, int* __restrict__ srcl)
{
  __shared__ float lw[384];
  __shared__ float lA[40], lB[40];
  __shared__ float4 lv4[136];
  __shared__ float sdt[128][4];
  if (blockIdx.x >= featBlocks){   // scatter part
    int e = (blockIdx.x - featBlocks)*256 + threadIdx.x;
    if (e >= NE_) return;
    int src, dst;
    if (e < E_){ src = ei[e]; dst = ei[E_ + e]; } else { src = dst = e - E_; }
    int pos = atomicAdd(&cursor[dst], 1);
    srcl[offs[dst] + pos] = src;
    return;
  }
  const int tid = threadIdx.x;
  load_convw(lw, wl1, wl2, wp1, wp2, wg, tid, 256);
  if (tid < 40){ lA[tid] = sA[tid]; lB[tid] = sB[tid]; }
  for (int i = tid; i < 136; i += 256)
    lv4[i] = make_float4(va1s[i], va1d[i], va1s[136+i], va1d[136+i]);
  __syncthreads();

  const int lane = tid & 63, wv = tid >> 6;
  const int nodeLocal = (wv >> 1)*64 + lane;     // 0..127
  const int half = wv & 1;                       // wave-uniform
  const int nodeIdx = blockIdx.x*128 + nodeLocal;
  const bool act = nodeIdx < m;
  const int gcl = base + (act ? nodeIdx : (m-1));
  int b = gcl / N0_, n = gcl - b*N0_;
  float xc[P_];
  const float* xp = x + (size_t)b*P_*N0_ + n;
  #pragma unroll
  for (int p = 0; p < P_; p++) xc[p] = xp[(size_t)p*N0_];

  float dt[4] = {0.f,0.f,0.f,0.f};
  u32 pk[4];
  u16* orow  = feat + (size_t)nodeIdx*160;
  auto emit = [&](int ch, float v){
    float t = fast_tanh(v);
    float4 vv = lv4[ch];
    dt[0] = fmaf(t, vv.x, dt[0]);
    dt[1] = fmaf(t, vv.y, dt[1]);
    dt[2] = fmaf(t, vv.z, dt[2]);
    dt[3] = fmaf(t, vv.w, dt[3]);
    u16 h  = f2u(t);
    int s = ch & 7;
    if ((s & 1) == 0){ pk[s>>1] = h; }
    else             { pk[s>>1] |= ((u32)h) << 16; }
    if (s == 7 && act){
      *(uint4*)(orow + (ch - 7)) = make_uint4(pk[0],pk[1],pk[2],pk[3]);
    }
  };

  float o4[4];
  if (half == 0){
    #pragma unroll
    for (int k = 0; k < 8; k++){
      conv_pool4<3,1,30>(xc, lw + k*3, lA[k], lB[k], o4);
      #pragma unroll
      for (int i = 0; i < 4; i++) emit(k*4+i, o4[i]);
    }
    #pragma unroll
    for (int k = 0; k < 8; k++){
      conv_pool4<5,1,28>(xc, lw + 24 + k*5, lA[8+k], lB[8+k], o4);
      #pragma unroll
      for (int i = 0; i < 4; i++) emit(32 + k*4+i, o4[i]);
    }
  } else {
    #pragma unroll
    for (int k = 0; k < 8; k++){
      conv_pool4<3,2,28>(xc, lw + 64 + k*3, lA[16+k], lB[16+k], o4);
      #pragma unroll
      for (int i = 0; i < 4; i++) emit(64 + k*4+i, o4[i]);
    }
    #pragma unroll
    for (int k = 0; k < 8; k++){
      conv_pool4<5,2,24>(xc, lw + 88 + k*5, lA[24+k], lB[24+k], o4);
      #pragma unroll
      for (int i = 0; i < 4; i++) emit(96 + k*4+i, o4[i]);
    }
    #pragma unroll
    for (int k = 0; k < 8; k++){
      float v = 0.f;
      #pragma unroll
      for (int j = 0; j < 32; j++) v = fmaf(lw[128 + k*32 + j], xc[j], v);
      emit(128 + k, fmaf(lA[32+k], v, lB[32+k]));
    }
  }

  if (half == 1){
    sdt[nodeLocal][0] = dt[0]; sdt[nodeLocal][1] = dt[1];
    sdt[nodeLocal][2] = dt[2]; sdt[nodeLocal][3] = dt[3];
  }
  __syncthreads();
  if (half == 0 && act){
    asrc1[(size_t)nodeIdx*2]   = dt[0] + sdt[nodeLocal][0];
    asrc1[(size_t)nodeIdx*2+1] = dt[2] + sdt[nodeLocal][2];
    adst1[(size_t)nodeIdx*2]   = dt[1] + sdt[nodeLocal][1];
    adst1[(size_t)nodeIdx*2+1] = dt[3] + sdt[nodeLocal][3];
  }
}

// ---------------- MFMA GEMM: MT m-tiles (16 rows each) per wave ----------------
template<int MT,int KT1,int KT2,int NT,int EPI,int LR2>
__global__ void __launch_bounds__(256) k_mfma(
    const u16* __restrict__ A1, int sA1,
    const u16* __restrict__ A2, int sA2,
    const u16* __restrict__ BT, int sBT,
    u16* __restrict__ C, int sC, int nbase,
    const float* __restrict__ bias, int m,
    const float* __restrict__ w2v, const float* __restrict__ bo2p, float* __restrict__ fout)
{
  const int wv = threadIdx.x >> 6, lane = threadIdx.x & 63;
  const int quad = lane >> 4, l15 = lane & 15;
  const int mb = blockIdx.x*(MT*64) + wv*(MT*16);
  int ar[MT];
  #pragma unroll
  for (int mt = 0; mt < MT; mt++) ar[mt] = min(mb + mt*16 + l15, m-1);

  v4f acc[MT][NT];
  #pragma unroll
  for (int mt = 0; mt < MT; mt++)
    #pragma unroll
    for (int nt = 0; nt < NT; nt++)
      acc[mt][nt] = (v4f){0.f,0.f,0.f,0.f};

  for (int kt = 0; kt < KT1+KT2; kt++){
    const u16* ab; int sA, koff;
    if (KT2 == 0 || kt < KT1){ ab = A1; sA = sA1; koff = kt*32; }
    else { ab = A2; sA = sA2; koff = (kt-KT1)*32; }
    v8s a[MT];
    #pragma unroll
    for (int mt = 0; mt < MT; mt++)
      a[mt] = *(const v8s*)(ab + (size_t)ar[mt]*sA + koff + quad*8);
    if (KT2 > 0 && LR2 && kt >= KT1){
      #pragma unroll
      for (int mt = 0; mt < MT; mt++)
        #pragma unroll
        for (int j = 0; j < 8; j++){
          float f = u2f((u16)a[mt][j]);
          f = f > 0.f ? f : 0.01f*f;
          a[mt][j] = (short)f2u(f);
        }
    }
    const int kb = kt*32 + quad*8;
    #pragma unroll
    for (int nt = 0; nt < NT; nt++){
      v8s b = *(const v8s*)(BT + (size_t)(nbase + nt*16 + l15)*sBT + kb);
      #pragma unroll
      for (int mt = 0; mt < MT; mt++)
        acc[mt][nt] = __builtin_amdgcn_mfma_f32_16x16x32_bf16(a[mt], b, acc[mt][nt], 0, 0, 0);
    }
  }

  if (EPI == 2){
    const float bo2v = bo2p[0];
    #pragma unroll
    for (int mt = 0; mt < MT; mt++){
      float part[4] = {0.f,0.f,0.f,0.f};
      #pragma unroll
      for (int nt = 0; nt < NT; nt++){
        const int col = nt*16 + l15;
        float wv2 = (col < 136) ? w2v[col] : 0.f;
        float bv  = bias[min(col,135)];
        #pragma unroll
        for (int i = 0; i < 4; i++){
          float xv = lrelu01(acc[mt][nt][i] + bv);
          part[i] = fmaf(xv, wv2, part[i]);
        }
      }
      #pragma unroll
      for (int i = 0; i < 4; i++){
        float v = part[i];
        v += __shfl_xor(v, 1, 64);
        v += __shfl_xor(v, 2, 64);
        v += __shfl_xor(v, 4, 64);
        v += __shfl_xor(v, 8, 64);
        int r = mb + mt*16 + quad*4 + i;
        if (l15 == 0 && r < m) fout[r] = v + bo2v;
      }
    }
    return;
  }

  #pragma unroll
  for (int mt = 0; mt < MT; mt++){
    const int r0 = mb + mt*16 + quad*4;
    #pragma unroll
    for (int nt = 0; nt < NT; nt++){
      const int col = nbase + nt*16 + l15;
      #pragma unroll
      for (int i = 0; i < 4; i++){
        int r = r0 + i;
        if (r < m){
          float xv = acc[mt][nt][i];
          if (EPI == 1){ xv += bias[min(col,135)]; xv = lrelu01(xv); }
          if (EPI == 3){ xv += bias[min(col,135)]; }
          C[(size_t)r*sC + col] = f2u(xv);
        }
      }
    }
  }
}

// ---------------- layer-1 GAT aggregation ----------------
// two degree-paired dst per wave (heavy-first); per-edge meta {off,c0,c1} in LDS;
// packed float2 accumulators (v_pk_fma_f32)
__global__ void __launch_bounds__(256) k_agg1(const u16* __restrict__ feat,
    const float* __restrict__ asrc, const float* __restrict__ adst,
    const int* __restrict__ offs, const int* __restrict__ srcl,
    const int* __restrict__ perm,
    u16* __restrict__ aggF,
    const float* __restrict__ v2s, const float* __restrict__ v2d,
    const float* __restrict__ cc,
    float* __restrict__ as_out, float* __restrict__ ad_out,
    int cbMask, int cbShift)
{
  __shared__ int4 smeta[4][2][32];
  const int tid = threadIdx.x;
  const int wv = tid >> 6, lane = tid & 63;
  const int half = lane >> 5, l32 = lane & 31;
  const int id = blockIdx.x;
  const int bb = id & cbMask;
  const int q = (id >> cbShift)*4 + wv;       // pair index
  const int dst = perm[N0_ - 1 - 2*q - half]; // heavy-degree first
  const int nbase = bb*N0_;
  const int node = nbase + dst;
  const int start = offs[dst], end = offs[dst+1];
  const int ne = end - start;

  const float ad0 = adst[(size_t)node*2], ad1v = adst[(size_t)node*2+1];
  const char* featB = (const char*)feat;

  v2f m01h0 = {0.f,0.f}, m23h0 = {0.f,0.f};
  v2f m01h1 = {0.f,0.f}, m23h1 = {0.f,0.f};
  v2f r01h0 = {0.f,0.f}, r01h1 = {0.f,0.f};

  auto acc_one = [&](int4 mt){
    const u16* fp = (const u16*)(featB + mt.x);
    float c0 = __int_as_float(mt.y), c1 = __int_as_float(mt.z);
    const uint2 hv = *(const uint2*)(fp + 4*l32);
    v2f f01 = unpack2(hv.x), f23 = unpack2(hv.y);
    v2f cc0 = {c0,c0}, cc1 = {c1,c1};
    m01h0 = __builtin_elementwise_fma(f01, cc0, m01h0);
    m23h0 = __builtin_elementwise_fma(f23, cc0, m23h0);
    m01h1 = __builtin_elementwise_fma(f01, cc1, m01h1);
    m23h1 = __builtin_elementwise_fma(f23, cc1, m23h1);
    if (l32 < 4){
      const u32 hr = *(const u32*)(fp + 128 + 2*l32);
      v2f g01 = unpack2(hr);
      r01h0 = __builtin_elementwise_fma(g01, cc0, r01h0);
      r01h1 = __builtin_elementwise_fma(g01, cc1, r01h1);
    }
  };
  auto acc_four = [&](int4 ma, int4 mb, int4 mc, int4 md){
    const u16* p0 = (const u16*)(featB + ma.x);
    const u16* p1 = (const u16*)(featB + mb.x);
    const u16* p2 = (const u16*)(featB + mc.x);
    const u16* p3 = (const u16*)(featB + md.x);
    const uint2 v0 = *(const uint2*)(p0 + 4*l32);
    const uint2 v1 = *(const uint2*)(p1 + 4*l32);
    const uint2 v2 = *(const uint2*)(p2 + 4*l32);
    const uint2 v3 = *(const uint2*)(p3 + 4*l32);
    u32 q0, q1, q2, q3;
    if (l32 < 4){
      q0 = *(const u32*)(p0 + 128 + 2*l32);
      q1 = *(const u32*)(p1 + 128 + 2*l32);
      q2 = *(const u32*)(p2 + 128 + 2*l32);
      q3 = *(const u32*)(p3 + 128 + 2*l32);
    }
    v2f f01, f23, cA, cB;
    #define EDGE1(vv, qq, mm) \
      f01 = unpack2(vv.x); f23 = unpack2(vv.y); \
      cA = (v2f){__int_as_float(mm.y), __int_as_float(mm.y)}; \
      cB = (v2f){__int_as_float(mm.z), __int_as_float(mm.z)}; \
      m01h0 = __builtin_elementwise_fma(f01, cA, m01h0); \
      m23h0 = __builtin_elementwise_fma(f23, cA, m23h0); \
      m01h1 = __builtin_elementwise_fma(f01, cB, m01h1); \
      m23h1 = __builtin_elementwise_fma(f23, cB, m23h1); \
      if (l32 < 4){ \
        v2f g01 = unpack2(qq); \
        r01h0 = __builtin_elementwise_fma(g01, cA, r01h0); \
        r01h1 = __builtin_elementwise_fma(g01, cB, r01h1); \
      }
    EDGE1(v0, q0, ma)
    EDGE1(v1, q1, mb)
    EDGE1(v2, q2, mc)
    EDGE1(v3, q3, md)
    #undef EDGE1
  };
  auto run_chunk = [&](int cnt){
    const int4* mp = &smeta[wv][half][0];
    int j = 0;
    for (; j + 3 < cnt; j += 4)
      acc_four(mp[j], mp[j+1], mp[j+2], mp[j+3]);
    for (; j < cnt; j++)
      acc_one(mp[j]);
  };

  if (ne <= 32){
    const bool has = l32 < ne;
    const int sn = nbase + (has ? srcl[start + l32] : 0);
    const int offL = sn * 320;
    float al0 = has ? lrelu02(asrc[(size_t)sn*2]   + ad0)  : -1e30f;
    float al1 = has ? lrelu02(asrc[(size_t)sn*2+1] + ad1v) : -1e30f;
    float mm = wred_max32(al0);
    float p0 = has ? __expf(al0 - mm) : 0.f;
    float c0 = p0 * (1.f/(wred_sum32(p0) + 1e-16f));
    mm = wred_max32(al1);
    float p1 = has ? __expf(al1 - mm) : 0.f;
    float c1 = p1 * (1.f/(wred_sum32(p1) + 1e-16f));
    if (has)
      smeta[wv][half][l32] = make_int4(offL, __float_as_int(c0), __float_as_int(c1), 0);
    asm volatile("s_waitcnt lgkmcnt(0)" ::: "memory");
    run_chunk(ne);
  } else {
    float lm0 = -1e30f, lm1 = -1e30f;
    for (int e = start + l32; e < end; e += 32){
      int sn = nbase + srcl[e];
      lm0 = fmaxf(lm0, lrelu02(asrc[(size_t)sn*2]   + ad0));
      lm1 = fmaxf(lm1, lrelu02(asrc[(size_t)sn*2+1] + ad1v));
    }
    float m0 = wred_max32(lm0), m1 = wred_max32(lm1);
    float ls0 = 0.f, ls1 = 0.f;
    for (int e = start + l32; e < end; e += 32){
      int sn = nbase + srcl[e];
      ls0 += __expf(lrelu02(asrc[(size_t)sn*2]   + ad0)  - m0);
      ls1 += __expf(lrelu02(asrc[(size_t)sn*2+1] + ad1v) - m1);
    }
    float si0 = 1.f/(wred_sum32(ls0) + 1e-16f);
    float si1 = 1.f/(wred_sum32(ls1) + 1e-16f);
    for (int cs = start; cs < end; cs += 32){
      int cnt = min(32, end - cs);
      bool has = l32 < cnt;
      int sn = nbase + (has ? srcl[cs + l32] : 0);
      int offL = sn * 320;
      float c0 = 0.f, c1 = 0.f;
      if (has){
        c0 = __expf(lrelu02(asrc[(size_t)sn*2]   + ad0)  - m0) * si0;
        c1 = __expf(lrelu02(asrc[(size_t)sn*2+1] + ad1v) - m1) * si1;
      }
      if (has)
        smeta[wv][half][l32] = make_int4(offL, __float_as_int(c0), __float_as_int(c1), 0);
      asm volatile("s_waitcnt lgkmcnt(0)" ::: "memory");
      run_chunk(cnt);
    }
  }

  u16* outp = aggF + (size_t)node*288;
  {
    ushort4 s0; s0.x=f2u(m01h0.x); s0.y=f2u(m01h0.y); s0.z=f2u(m23h0.x); s0.w=f2u(m23h0.y);
    *(ushort4*)(outp + 4*l32) = s0;
    ushort4 s1; s1.x=f2u(m01h1.x); s1.y=f2u(m01h1.y); s1.z=f2u(m23h1.x); s1.w=f2u(m23h1.y);
    *(ushort4*)(outp + 136 + 4*l32) = s1;
    if (l32 < 4){
      ushort2 t0; t0.x=f2u(r01h0.x); t0.y=f2u(r01h0.y);
      *(ushort2*)(outp + 128 + 2*l32) = t0;
      ushort2 t1; t1.x=f2u(r01h1.x); t1.y=f2u(r01h1.y);
      *(ushort2*)(outp + 136 + 128 + 2*l32) = t1;
    }
  }
  {
    int c = 4*l32;
    float s = m01h0.x*v2s[c] + m01h0.y*v2s[c+1] + m23h0.x*v2s[c+2] + m23h0.y*v2s[c+3]
            + m01h1.x*v2s[136+c] + m01h1.y*v2s[136+c+1] + m23h1.x*v2s[136+c+2] + m23h1.y*v2s[136+c+3];
    float d = m01h0.x*v2d[c] + m01h0.y*v2d[c+1] + m23h0.x*v2d[c+2] + m23h0.y*v2d[c+3]
            + m01h1.x*v2d[136+c] + m01h1.y*v2d[136+c+1] + m23h1.x*v2d[136+c+2] + m23h1.y*v2d[136+c+3];
    if (l32 < 4){
      int cr = 128 + 2*l32;
      s += r01h0.x*v2s[cr] + r01h0.y*v2s[cr+1] + r01h1.x*v2s[136+cr] + r01h1.y*v2s[136+cr+1];
      d += r01h0.x*v2d[cr] + r01h0.y*v2d[cr+1] + r01h1.x*v2d[136+cr] + r01h1.y*v2d[136+cr+1];
    }
    s = wred_sum32(s); d = wred_sum32(d);
    if (l32 == 0){ as_out[node] = s + cc[0]; ad_out[node] = d + cc[1]; }
  }
}

// ---------------- layer-2 GAT aggregation (H=1) ----------------
__global__ void __launch_bounds__(256) k_agg2(const u16* __restrict__ h, int sh,
    const float* __restrict__ asrc, const float* __restrict__ adst,
    const int* __restrict__ offs, const int* __restrict__ srcl,
    const int* __restrict__ perm,
    const float* __restrict__ bias, u16* __restrict__ outp0, int so,
    int cbMask, int cbShift)
{
  __shared__ int2 smeta[4][2][32];
  const int tid = threadIdx.x;
  const int wv = tid >> 6, lane = tid & 63;
  const int half = lane >> 5, l32 = lane & 31;
  const int id = blockIdx.x;
  const int bb = id & cbMask;
  const int q = (id >> cbShift)*4 + wv;
  const int dst = perm[N0_ - 1 - 2*q - half]; // heavy-degree first
  const int nbase = bb*N0_;
  const int node = nbase + dst;
  const int start = offs[dst], end = offs[dst+1];
  const int ne = end - start;
  const int bstride = 2*sh;

  const float adh = adst[node];
  const char* hB = (const char*)h;

  v2f a01 = {0.f,0.f}, a23 = {0.f,0.f}, r01 = {0.f,0.f};

  auto acc_one = [&](int2 mt){
    const u16* hp = (const u16*)(hB + mt.x);
    float c0 = __int_as_float(mt.y);
    const uint2 hv = *(const uint2*)(hp + 4*l32);
    v2f cc0 = {c0,c0};
    a01 = __builtin_elementwise_fma(unpack2(hv.x), cc0, a01);
    a23 = __builtin_elementwise_fma(unpack2(hv.y), cc0, a23);
    if (l32 < 4){
      const u32 hr = *(const u32*)(hp + 128 + 2*l32);
      r01 = __builtin_elementwise_fma(unpack2(hr), cc0, r01);
    }
  };
  auto acc_four = [&](int2 ma, int2 mb, int2 mc, int2 md){
    const u16* p0 = (const u16*)(hB + ma.x);
    const u16* p1 = (const u16*)(hB + mb.x);
    const u16* p2 = (const u16*)(hB + mc.x);
    const u16* p3 = (const u16*)(hB + md.x);
    const uint2 v0 = *(const uint2*)(p0 + 4*l32);
    const uint2 v1 = *(const uint2*)(p1 + 4*l32);
    const uint2 v2 = *(const uint2*)(p2 + 4*l32);
    const uint2 v3 = *(const uint2*)(p3 + 4*l32);
    u32 q0, q1, q2, q3;
    if (l32 < 4){
      q0 = *(const u32*)(p0 + 128 + 2*l32);
      q1 = *(const u32*)(p1 + 128 + 2*l32);
      q2 = *(const u32*)(p2 + 128 + 2*l32);
      q3 = *(const u32*)(p3 + 128 + 2*l32);
    }
    v2f cc;
    #define EDGE2(vv, qq, mm) \
      cc = (v2f){__int_as_float(mm.y), __int_as_float(mm.y)}; \
      a01 = __builtin_elementwise_fma(unpack2(vv.x), cc, a01); \
      a23 = __builtin_elementwise_fma(unpack2(vv.y), cc, a23); \
      if (l32 < 4) r01 = __builtin_elementwise_fma(unpack2(qq), cc, r01);
    EDGE2(v0, q0, ma)
    EDGE2(v1, q1, mb)
    EDGE2(v2, q2, mc)
    EDGE2(v3, q3, md)
    #undef EDGE2
  };
  auto run_chunk = [&](int cnt){
    const int2* mp = &smeta[wv][half][0];
    int j = 0;
    for (; j + 3 < cnt; j += 4)
      acc_four(mp[j], mp[j+1], mp[j+2], mp[j+3]);
    for (; j < cnt; j++)
      acc_one(mp[j]);
  };

  if (ne <= 32){
    const bool has = l32 < ne;
    const int sn = nbase + (has ? srcl[start + l32] : 0);
    const int offL = sn * bstride;
    float al = has ? lrelu02(asrc[sn] + adh) : -1e30f;
    float m = wred_max32(al);
    float p = has ? __expf(al - m) : 0.f;
    float c0 = p * (1.f/(wred_sum32(p) + 1e-16f));
    if (has)
      smeta[wv][half][l32] = make_int2(offL, __float_as_int(c0));
    asm volatile("s_waitcnt lgkmcnt(0)" ::: "memory");
    run_chunk(ne);
  } else {
    float lm = -1e30f;
    for (int e = start + l32; e < end; e += 32){
      int sn = nbase + srcl[e];
      lm = fmaxf(lm, lrelu02(asrc[sn] + adh));
    }
    float m = wred_max32(lm);
    float ls = 0.f;
    for (int e = start + l32; e < end; e += 32){
      int sn = nbase + srcl[e];
      ls += __expf(lrelu02(asrc[sn] + adh) - m);
    }
    float si = 1.f/(wred_sum32(ls) + 1e-16f);
    for (int cs = start; cs < end; cs += 32){
      int cnt = min(32, end - cs);
      bool has = l32 < cnt;
      int sn = nbase + (has ? srcl[cs + l32] : 0);
      int offL = sn * bstride;
      float c0 = has ? __expf(lrelu02(asrc[sn] + adh) - m) * si : 0.f;
      if (has)
        smeta[wv][half][l32] = make_int2(offL, __float_as_int(c0));
      asm volatile("s_waitcnt lgkmcnt(0)" ::: "memory");
      run_chunk(cnt);
    }
  }

  u16* outp = outp0 + (size_t)node*so;
  {
    int c = 4*l32;
    ushort4 st;
    st.x = f2u(lrelu01(a01.x + bias[c]));
    st.y = f2u(lrelu01(a01.y + bias[c+1]));
    st.z = f2u(lrelu01(a23.x + bias[c+2]));
    st.w = f2u(lrelu01(a23.y + bias[c+3]));
    *(ushort4*)(outp + c) = st;
    if (l32 < 4){
      int cr = 128 + 2*l32;
      ushort2 sr;
      sr.x = f2u(lrelu01(r01.x + bias[cr]));
      sr.y = f2u(lrelu01(r01.y + bias[cr+1]));
      *(ushort2*)(outp + cr) = sr;
    }
  }
}

// ---------------- launch ----------------
extern "C" void kernel_launch(void* const* d_in, const int* in_sizes, int n_in,
                              void* d_out, int out_size, void* d_ws, size_t ws_size,
                              hipStream_t stream)
{
  (void)in_sizes; (void)n_in; (void)out_size;
  const float* x    = (const float*)d_in[0];
  const float* wl1  = (const float*)d_in[1];
  const float* gl1  = (const float*)d_in[3];
  const float* bel1 = (const float*)d_in[4];
  const float* wl2  = (const float*)d_in[5];
  const float* gl2  = (const float*)d_in[7];
  const float* bel2 = (const float*)d_in[8];
  const float* wp1  = (const float*)d_in[9];
  const float* gp1  = (const float*)d_in[11];
  const float* bep1 = (const float*)d_in[12];
  const float* wp2  = (const float*)d_in[13];
  const float* gp2  = (const float*)d_in[15];
  const float* bep2 = (const float*)d_in[16];
  const float* wg   = (const float*)d_in[17];
  const float* gg   = (const float*)d_in[19];
  const float* beg  = (const float*)d_in[20];
  const float* W1   = (const float*)d_in[21];
  const float* as1  = (const float*)d_in[22];
  const float* ad1  = (const float*)d_in[23];
  const float* bb1  = (const float*)d_in[24];
  const float* W2   = (const float*)d_in[25];
  const float* as2  = (const float*)d_in[26];
  const float* ad2  = (const float*)d_in[27];
  const float* bb2  = (const float*)d_in[28];
  const float* Wo   = (const float*)d_in[29];
  const float* bo   = (const float*)d_in[30];
  const float* Wo2  = (const float*)d_in[31];
  const float* bo2  = (const float*)d_in[32];
  const int*   ei   = (const int*)d_in[33];

  const size_t STATIC_BYTES = 1250000;
  int nc = 1;
  while (nc < 8 && STATIC_BYTES + (size_t)1560*(NODES/nc) > ws_size) nc <<= 1;
  const int CB = B_/nc, CN = CB*N0_;
  int cbShift = 0; while ((1 << cbShift) < CB) cbShift++;
  const int cbMask = CB - 1;

  char* wsb = (char*)d_ws; size_t off = 0;
  auto alloc = [&](size_t nbytes)->void*{
    void* p = wsb + off; off = (off + nbytes + 255) & ~(size_t)255; return p;
  };
  int*   zbase  = (int*)  alloc(20080*sizeof(int));
  float* gsum   = (float*)zbase;
  float* gsq    = gsum + 40;
  int*   counts = zbase + 80;
  int*   cursor = counts + 10000;
  float* sA     = (float*)alloc(40*sizeof(float));
  float* sB     = (float*)alloc(40*sizeof(float));
  int*   offs   = (int*)  alloc(10001*sizeof(int));
  int*   srcl   = (int*)  alloc((size_t)NE_*sizeof(int));
  int*   perm   = (int*)  alloc((size_t)N0_*sizeof(int));
  u16*   W12T   = (u16*)  alloc((size_t)144*288*2);
  u16*   WoT    = (u16*)  alloc((size_t)144*320*2);
  float* va1s   = (float*)alloc(272*sizeof(float));
  float* va1d   = (float*)alloc(272*sizeof(float));
  float* v2ss   = (float*)alloc(272*sizeof(float));
  float* v2dd   = (float*)alloc(272*sizeof(float));
  float* ccv    = (float*)alloc(2*sizeof(float));
  float* b12    = (float*)alloc(136*sizeof(float));
  u16*   feat   = (u16*)  alloc((size_t)CN*160*2);
  u16*   aggF   = (u16*)  alloc((size_t)CN*288*2);
  u16*   h2     = (u16*)  alloc((size_t)CN*144*2);
  u16*   g2l    = (u16*)  alloc((size_t)CN*160*2);
  float* asrc1  = (float*)alloc((size_t)CN*2*sizeof(float));
  float* adst1  = (float*)alloc((size_t)CN*2*sizeof(float));
  float* asrc2  = (float*)alloc((size_t)CN*sizeof(float));
  float* adst2  = (float*)alloc((size_t)CN*sizeof(float));

  hipMemsetAsync(zbase, 0, 20080*sizeof(int), stream);

  // K1: setup(346) + bn_stats(625) + count-hist(665)
  k_mega1<<<1636,256,0,stream>>>(Wo, WoT, W1, W2, W12T,
                                 as1, ad1, va1s, va1d, as2, ad2, bb1,
                                 v2ss, v2dd, ccv, b12,
                                 x, wl1, wl2, wp1, wp2, wg, gsum, gsq,
                                 ei, counts);

  // K2: bn_fin + scan + perm
  k_mega2<<<3,1024,0,stream>>>(counts, offs, perm, gsum, gsq, sA, sB,
                               gl1,gl2,gp1,gp2,gg, bel1,bel2,bep1,bep2,beg);

  const int gxm = (CN + 127)/128;     // MT=2: 128 rows/block
  const int gx2 = (CN + 127)/128;
  const int aggB = 1250*CB;
  for (int c = 0; c < nc; c++){
    const int base = c*CN;

    // K3: feat + (first chunk only) scatter
    const int extra = (c == 0) ? 665 : 0;
    k_feat_sc<<<gx2 + extra,256,0,stream>>>(x, wl1,wl2,wp1,wp2,wg, sA, sB, va1s, va1d,
                                            feat, asrc1, adst1, base, CN, gx2,
                                            ei, offs, cursor, srcl);

    k_agg1<<<aggB,256,0,stream>>>(feat, asrc1, adst1, offs, srcl, perm, aggF,
                                  v2ss, v2dd, ccv, asrc2, adst2, cbMask, cbShift);

    k_mfma<2,9,0,9,3,0><<<gxm,256,0,stream>>>(aggF,288, (const u16*)0,0, W12T,288, h2,144, 0, b12, CN,
                                              (const float*)0,(const float*)0,(float*)0);

    k_agg2<<<aggB,256,0,stream>>>(h2,144, asrc2, adst2, offs, srcl, perm, bb2, g2l,160,
                                  cbMask, cbShift);

    // final: A2 = feat with on-load lrelu (LR2=1) — featL buffer eliminated
    k_mfma<2,5,5,9,2,1><<<gxm,256,0,stream>>>(g2l,160, feat,160, WoT,320, (u16*)0,0, 0, bo, CN,
                                              Wo2, bo2, (float*)d_out + base);
  }
}